// Round 4
// baseline (187.610 us; speedup 1.0000x reference)
//
#include <hip/hip_runtime.h>
#include <hip/hip_bf16.h>
#include <math.h>

// TinyMoE: out = sum_e softmax(x@Wr)[e] * (gelu(x@w1[e]+b1[e]) @ w2[e] + b2[e])
// Two dense GEMMs: [32768x512]@[512x256] -> gelu/scale -> @[256x512(+b2 rows)]
// bf16 MFMA (16x16x32), fp32 router/softmax/gelu.
// R4: wave-private design -- each wave owns 16 tokens end-to-end in its own
// LDS region. ZERO __syncthreads(). Coalesced staging kept (R3 lesson: direct
// global A-frags scatter 2KB-strided -> latency-bound). 8 decoupled waves/CU.

typedef short v8s __attribute__((ext_vector_type(8)));
typedef float v4f __attribute__((ext_vector_type(4)));

#define XS 520   // X row stride (bf16): 512 + 8 pad (2-way bank alias max = free)
#define HS 296   // H row stride (bf16): 288 + 8 pad

__device__ __forceinline__ unsigned short f2bf(float f) {
    unsigned int u = __builtin_bit_cast(unsigned int, f);
    u += 0x7fffu + ((u >> 16) & 1u);
    return (unsigned short)(u >> 16);
}

// ---- prep: pack weights into bf16 MFMA B-fragment layout in workspace ----
// Block = 16(N) x 32(K) bf16, stored as [n_local*32 + k_local], 512 elems = 1KB.
// Lane l reads 16B at ((l&15)*32 + (l>>4)*8)*2 -> B[k][n], n=l&15, k=(l>>4)*8+j.
__global__ void moe_prep(const float* __restrict__ w1,   // (4,512,64)
                         const float* __restrict__ w2,   // (4,64,512)
                         const float* __restrict__ b2,   // (4,512)
                         const float* __restrict__ rw,   // (512,4)
                         unsigned short* __restrict__ w1p,
                         unsigned short* __restrict__ w2p,
                         unsigned short* __restrict__ rp) {
    int idx = blockIdx.x * 256 + threadIdx.x;
    if (idx < 131072) {
        // W1' [K=512][N=256], block = kb*16 + cb
        int block = idx >> 9, within = idx & 511;
        int kb = block >> 4, cb = block & 15;
        int n = within >> 5, kl = within & 31;
        int k = kb * 32 + kl;
        int col = cb * 16 + n;
        int e = col >> 6, h = col & 63;
        w1p[idx] = f2bf(w1[(e * 512 + k) * 64 + h]);
    } else if (idx < 131072 + 147456) {
        // W2' [Kpad=288][N=512], block = kb*32 + cb. k in [256,260) = b2 rows, >=260 zero.
        int op = idx - 131072;
        int block = op >> 9, within = op & 511;
        int kb = block >> 5, cb = block & 31;
        int n = within >> 5, kl = within & 31;
        int k = kb * 32 + kl;
        int d = cb * 16 + n;
        float v = 0.f;
        if (k < 256) {
            int e = k >> 6, h = k & 63;
            v = w2[(e * 64 + h) * 512 + d];
        } else if (k < 260) {
            v = b2[(k - 256) * 512 + d];
        }
        w2p[op] = f2bf(v);
    } else if (idx < 131072 + 147456 + 8192) {
        // router W [K=512][N=16] (cols >=4 zero), block = kb
        int op = idx - (131072 + 147456);
        int kb = op >> 9, within = op & 511;
        int n = within >> 5, kl = within & 31;
        int k = kb * 32 + kl;
        float v = (n < 4) ? rw[k * 4 + n] : 0.f;
        rp[op] = f2bf(v);
    }
}

// ---- main fused kernel: one wave = 16 tokens, no WG barriers ----
__global__ __launch_bounds__(256, 2)
void moe_main(const float* __restrict__ x,
              const float* __restrict__ rb,
              const float* __restrict__ b1,
              const unsigned short* __restrict__ w1p,
              const unsigned short* __restrict__ w2p,
              const unsigned short* __restrict__ rp,
              float* __restrict__ out) {
    // 4 wave-private X regions [16][XS]; H [16][HS] overlays X after GEMM1.
    __shared__ __align__(16) unsigned short lx[4 * 16 * XS];   // 66560 B
    __shared__ float llog[4 * 16 * 4];                         // 1 KB
    __shared__ float lw[4 * 16 * 4];                           // 1 KB

    const int tid  = threadIdx.x;
    const int lane = tid & 63, wv = tid >> 6;
    const int lr = lane & 15, lq = lane >> 4;   // A: m=lr, k=lq*8+j ; B: n=lr ; C: col=lr, row=lq*4+r
    const long t0 = (long)blockIdx.x * 64 + wv * 16;   // this wave's 16 tokens

    unsigned short* W  = lx + wv * 16 * XS;     // wave-private
    float* wlog = llog + wv * 64;
    float* wlw  = lw   + wv * 64;

    // ---- stage: 16 rows x 512 fp32 -> bf16 LDS, coalesced (lane-contig float4) ----
    const float4* xt = (const float4*)(x + t0 * 512);
    #pragma unroll
    for (int it = 0; it < 32; ++it) {
        int F = it * 64 + lane;            // float4 index in 16x512 tile (2048 total)
        int row = F >> 7, c4 = F & 127;
        float4 v = xt[F];
        unsigned int p0 = (unsigned int)f2bf(v.x) | ((unsigned int)f2bf(v.y) << 16);
        unsigned int p1 = (unsigned int)f2bf(v.z) | ((unsigned int)f2bf(v.w) << 16);
        *(uint2*)&W[row * XS + c4 * 4] = make_uint2(p0, p1);
    }
    // compiler inserts lgkmcnt/vmcnt waits on dataflow; same-wave only, no barrier

    // ---- router: logits for own 16 tokens, within-wave softmax ----
    {
        v4f accR; accR[0] = accR[1] = accR[2] = accR[3] = 0.f;
        #pragma unroll
        for (int kb = 0; kb < 16; ++kb) {
            v8s a = *(const v8s*)(const void*)&W[lr * XS + kb * 32 + lq * 8];
            v8s b = *(const v8s*)(const void*)&rp[kb * 512 + lr * 32 + lq * 8];
            accR = __builtin_amdgcn_mfma_f32_16x16x32_bf16(a, b, accR, 0, 0, 0);
        }
        if (lr < 4) {
            #pragma unroll
            for (int r = 0; r < 4; ++r)
                wlog[(lq * 4 + r) * 4 + lr] = accR[r];
        }
        asm volatile("s_waitcnt lgkmcnt(0)" ::: "memory");
        if (lane < 16) {
            float l[4];
            #pragma unroll
            for (int e = 0; e < 4; ++e) l[e] = wlog[lane * 4 + e] + rb[e];
            float mx = fmaxf(fmaxf(l[0], l[1]), fmaxf(l[2], l[3]));
            float ex[4], s = 0.f;
            #pragma unroll
            for (int e = 0; e < 4; ++e) { ex[e] = expf(l[e] - mx); s += ex[e]; }
            float inv = 1.f / s;
            #pragma unroll
            for (int e = 0; e < 4; ++e) wlw[lane * 4 + e] = ex[e] * inv;
        }
        asm volatile("s_waitcnt lgkmcnt(0)" ::: "memory");
    }

    // ---- GEMM1: C1[16][256] = X @ W1' (all 16 n-tiles in one pass) ----
    v4f acc1[16];
    #pragma unroll
    for (int nt = 0; nt < 16; ++nt)
        acc1[nt][0] = acc1[nt][1] = acc1[nt][2] = acc1[nt][3] = 0.f;

    for (int kb = 0; kb < 16; ++kb) {
        v8s a = *(const v8s*)(const void*)&W[lr * XS + kb * 32 + lq * 8];
        #pragma unroll
        for (int nt = 0; nt < 16; ++nt) {
            v8s b = *(const v8s*)(const void*)&w1p[(size_t)(kb * 16 + nt) * 512 + lr * 32 + lq * 8];
            acc1[nt] = __builtin_amdgcn_mfma_f32_16x16x32_bf16(a, b, acc1[nt], 0, 0, 0);
        }
    }
    asm volatile("s_waitcnt lgkmcnt(0)" ::: "memory");  // all X reads done; overlay H on X region

    // ---- epilogue: gelu(v+b1)*router_weight -> bf16 H[16][288] in wave-private LDS ----
    {
        #pragma unroll
        for (int nt = 0; nt < 16; ++nt) {
            float bb = b1[nt * 16 + lr];           // col = nt*16+lr, b1 flat (4,64)=256
            float wt4[4];
            #pragma unroll
            for (int r = 0; r < 4; ++r) wt4[r] = wlw[(lq * 4 + r) * 4 + (nt >> 2)];
            #pragma unroll
            for (int r = 0; r < 4; ++r) {
                int row = lq * 4 + r;
                float v = acc1[nt][r] + bb;
                float g = 0.5f * v * (1.f + erff(v * 0.70710678118f)) * wt4[r];
                W[row * HS + nt * 16 + lr] = f2bf(g);
            }
        }
        // cols 256..259 = router weights (pair with b2 rows of W2'); 260..287 zero
        #pragma unroll
        for (int i = 0; i < 8; ++i) {
            int idx = i * 64 + lane;               // 16 rows x 32 cols
            int row = idx >> 5, c = idx & 31;
            unsigned short v = (c < 4) ? f2bf(wlw[row * 4 + c]) : (unsigned short)0;
            W[row * HS + 256 + c] = v;
        }
    }
    asm volatile("s_waitcnt lgkmcnt(0)" ::: "memory");

    // ---- GEMM2: OUT[16][512] = H[16][288] @ W2', 2 N-passes of 256 ----
    float* ot = out + t0 * 512;
    #pragma unroll
    for (int np = 0; np < 2; ++np) {
        v4f acc2[16];
        #pragma unroll
        for (int nt = 0; nt < 16; ++nt)
            acc2[nt][0] = acc2[nt][1] = acc2[nt][2] = acc2[nt][3] = 0.f;

        for (int kb = 0; kb < 9; ++kb) {
            v8s a = *(const v8s*)(const void*)&W[lr * HS + kb * 32 + lq * 8];
            #pragma unroll
            for (int nt = 0; nt < 16; ++nt) {
                v8s b = *(const v8s*)(const void*)&w2p[(size_t)(kb * 32 + np * 16 + nt) * 512 + lr * 32 + lq * 8];
                acc2[nt] = __builtin_amdgcn_mfma_f32_16x16x32_bf16(a, b, acc2[nt], 0, 0, 0);
            }
        }

        #pragma unroll
        for (int nt = 0; nt < 16; ++nt)
            #pragma unroll
            for (int r = 0; r < 4; ++r) {
                int row = lq * 4 + r;
                int col = np * 256 + nt * 16 + lr;
                ot[row * 512 + col] = acc2[nt][r];
            }
    }
}

extern "C" void kernel_launch(void* const* d_in, const int* in_sizes, int n_in,
                              void* d_out, int out_size, void* d_ws, size_t ws_size,
                              hipStream_t stream) {
    const float* x  = (const float*)d_in[0];
    const float* rw = (const float*)d_in[1];
    const float* rb = (const float*)d_in[2];
    const float* w1 = (const float*)d_in[3];
    const float* b1 = (const float*)d_in[4];
    const float* w2 = (const float*)d_in[5];
    const float* b2 = (const float*)d_in[6];

    unsigned short* w1p = (unsigned short*)d_ws;      // 131072 elems
    unsigned short* w2p = w1p + 131072;               // 147456 elems
    unsigned short* rp  = w2p + 147456;               // 8192 elems  (total ~573 KB)

    moe_prep<<<1120, 256, 0, stream>>>(w1, w2, b2, rw, w1p, w2p, rp);
    moe_main<<<512, 256, 0, stream>>>(x, rb, b1, w1p, w2p, rp, (float*)d_out);
}

// Round 5
// 149.355 us; speedup vs baseline: 1.2561x; 1.2561x over previous
//
#include <hip/hip_runtime.h>
#include <hip/hip_bf16.h>
#include <math.h>

// TinyMoE: out = sum_e softmax(x@Wr)[e] * (gelu(x@w1[e]+b1[e]) @ w2[e] + b2[e])
// Two dense GEMMs: [32768x512]@[512x256] -> gelu/scale -> @[256x512(+b2 rows)]
// bf16 MFMA (16x16x32), fp32 router/softmax/gelu.
// R5: 512-thread WG (8 waves), TT=32, LDS 34 KB -> 4 WG/CU x 8 waves =
// 32 waves/CU (100% occupancy) with R2's traffic profile. Register-lean
// (acc<=16) to hold 64 VGPR for 8 waves/SIMD. 3 barriers.

typedef short v8s __attribute__((ext_vector_type(8)));
typedef float v4f __attribute__((ext_vector_type(4)));

#define XS 520   // X row stride (bf16): 512 + 8 pad
#define HS 296   // H row stride (bf16): 288 + 8 pad
#define TT 32    // tokens per WG

__device__ __forceinline__ unsigned short f2bf(float f) {
    unsigned int u = __builtin_bit_cast(unsigned int, f);
    u += 0x7fffu + ((u >> 16) & 1u);
    return (unsigned short)(u >> 16);
}

// ---- prep: pack weights into bf16 MFMA B-fragment layout in workspace ----
// Block = 16(N) x 32(K) bf16, stored as [n_local*32 + k_local], 512 elems = 1KB.
// Lane l reads 16B at ((l&15)*32 + (l>>4)*8)*2 -> B[k][n], n=l&15, k=(l>>4)*8+j.
__global__ void moe_prep(const float* __restrict__ w1,   // (4,512,64)
                         const float* __restrict__ w2,   // (4,64,512)
                         const float* __restrict__ b2,   // (4,512)
                         const float* __restrict__ rw,   // (512,4)
                         unsigned short* __restrict__ w1p,
                         unsigned short* __restrict__ w2p,
                         unsigned short* __restrict__ rp) {
    int idx = blockIdx.x * 256 + threadIdx.x;
    if (idx < 131072) {
        // W1' [K=512][N=256], block = kb*16 + cb
        int block = idx >> 9, within = idx & 511;
        int kb = block >> 4, cb = block & 15;
        int n = within >> 5, kl = within & 31;
        int k = kb * 32 + kl;
        int col = cb * 16 + n;
        int e = col >> 6, h = col & 63;
        w1p[idx] = f2bf(w1[(e * 512 + k) * 64 + h]);
    } else if (idx < 131072 + 147456) {
        // W2' [Kpad=288][N=512], block = kb*32 + cb. k in [256,260) = b2 rows, >=260 zero.
        int op = idx - 131072;
        int block = op >> 9, within = op & 511;
        int kb = block >> 5, cb = block & 31;
        int n = within >> 5, kl = within & 31;
        int k = kb * 32 + kl;
        int d = cb * 16 + n;
        float v = 0.f;
        if (k < 256) {
            int e = k >> 6, h = k & 63;
            v = w2[(e * 64 + h) * 512 + d];
        } else if (k < 260) {
            v = b2[(k - 256) * 512 + d];
        }
        w2p[op] = f2bf(v);
    } else if (idx < 131072 + 147456 + 8192) {
        // router W [K=512][N=16] (cols >=4 zero), block = kb
        int op = idx - (131072 + 147456);
        int kb = op >> 9, within = op & 511;
        int n = within >> 5, kl = within & 31;
        int k = kb * 32 + kl;
        float v = (n < 4) ? rw[k * 4 + n] : 0.f;
        rp[op] = f2bf(v);
    }
}

// ---- main fused kernel: 512 threads = 8 waves per 32-token tile ----
__global__ __launch_bounds__(512, 8)
void moe_main(const float* __restrict__ x,
              const float* __restrict__ rb,
              const float* __restrict__ b1,
              const unsigned short* __restrict__ w1p,
              const unsigned short* __restrict__ w2p,
              const unsigned short* __restrict__ rp,
              float* __restrict__ out) {
    // X tile [TT][XS] bf16 = 33280 B; H tile [TT][HS] (18944 B) overlays after GEMM1.
    __shared__ __align__(16) unsigned short lx[TT * XS];
    __shared__ float llog[TT * 4];
    __shared__ float lw[TT * 4];

    const int tid  = threadIdx.x;
    const int lane = tid & 63, wv = tid >> 6;   // wv in [0,8)
    const int lr = lane & 15, lq = lane >> 4;   // A: m=lr, k=lq*8+j ; B: n=lr ; C: col=lr, row=lq*4+r
    const long t0 = (long)blockIdx.x * TT;

    // ---- phase 0: stage X tile (fp32 global -> bf16 LDS), coalesced ----
    const float4* xt = (const float4*)(x + t0 * 512);
    #pragma unroll
    for (int it = 0; it < 8; ++it) {
        int F = it * 512 + tid;            // float4 index in 32x512 tile (4096 total)
        int row = F >> 7, c4 = F & 127;
        float4 v = xt[F];
        unsigned int p0 = (unsigned int)f2bf(v.x) | ((unsigned int)f2bf(v.y) << 16);
        unsigned int p1 = (unsigned int)f2bf(v.z) | ((unsigned int)f2bf(v.w) << 16);
        *(uint2*)&lx[row * XS + c4 * 4] = make_uint2(p0, p1);
    }
    __syncthreads();

    // ---- phase 1: router on waves 0,1 (16 tokens each), within-wave softmax ----
    if (wv < 2) {
        v4f accR; accR[0] = accR[1] = accR[2] = accR[3] = 0.f;
        #pragma unroll
        for (int kb = 0; kb < 16; ++kb) {
            v8s a = *(const v8s*)(const void*)&lx[(16 * wv + lr) * XS + kb * 32 + lq * 8];
            v8s b = *(const v8s*)(const void*)&rp[kb * 512 + lr * 32 + lq * 8];
            accR = __builtin_amdgcn_mfma_f32_16x16x32_bf16(a, b, accR, 0, 0, 0);
        }
        if (lr < 4) {
            #pragma unroll
            for (int r = 0; r < 4; ++r)
                llog[(16 * wv + lq * 4 + r) * 4 + lr] = accR[r];
        }
        asm volatile("s_waitcnt lgkmcnt(0)" ::: "memory");
        if (lane < 16) {
            int t = 16 * wv + lane;
            float l[4];
            #pragma unroll
            for (int e = 0; e < 4; ++e) l[e] = llog[t * 4 + e] + rb[e];
            float mx = fmaxf(fmaxf(l[0], l[1]), fmaxf(l[2], l[3]));
            float ex[4], s = 0.f;
            #pragma unroll
            for (int e = 0; e < 4; ++e) { ex[e] = expf(l[e] - mx); s += ex[e]; }
            float inv = 1.f / s;
            #pragma unroll
            for (int e = 0; e < 4; ++e) lw[t * 4 + e] = ex[e] * inv;
        }
    }

    // ---- phase 2: GEMM1  C1[32][256] = X @ W1'; wave w owns cols [32w, 32w+32) ----
    v4f acc1[2][2];
    #pragma unroll
    for (int mt = 0; mt < 2; ++mt)
        #pragma unroll
        for (int nt = 0; nt < 2; ++nt)
            acc1[mt][nt][0] = acc1[mt][nt][1] = acc1[mt][nt][2] = acc1[mt][nt][3] = 0.f;

    for (int kb = 0; kb < 16; ++kb) {
        v8s a[2], b[2];
        #pragma unroll
        for (int mt = 0; mt < 2; ++mt)
            a[mt] = *(const v8s*)(const void*)&lx[(16 * mt + lr) * XS + kb * 32 + lq * 8];
        #pragma unroll
        for (int nt = 0; nt < 2; ++nt)
            b[nt] = *(const v8s*)(const void*)&w1p[(size_t)(kb * 16 + 2 * wv + nt) * 512 + lr * 32 + lq * 8];
        #pragma unroll
        for (int mt = 0; mt < 2; ++mt)
            #pragma unroll
            for (int nt = 0; nt < 2; ++nt)
                acc1[mt][nt] = __builtin_amdgcn_mfma_f32_16x16x32_bf16(a[mt], b[nt], acc1[mt][nt], 0, 0, 0);
    }
    __syncthreads();   // X reads done by all waves; lw published; H may overlay lx

    // ---- epilogue: gelu(v+b1)*router_weight -> bf16 H[32][288] ----
    {
        const int e = wv >> 1;            // expert for this wave's 32-col slab
        float b1v[2];
        #pragma unroll
        for (int nt = 0; nt < 2; ++nt) b1v[nt] = b1[32 * wv + nt * 16 + lr];
        #pragma unroll
        for (int mt = 0; mt < 2; ++mt) {
            #pragma unroll
            for (int r = 0; r < 4; ++r) {
                int row = 16 * mt + lq * 4 + r;
                float wt = lw[row * 4 + e];
                #pragma unroll
                for (int nt = 0; nt < 2; ++nt) {
                    float v = acc1[mt][nt][r] + b1v[nt];
                    float g = 0.5f * v * (1.f + erff(v * 0.70710678118f)) * wt;
                    lx[row * HS + 32 * wv + nt * 16 + lr] = f2bf(g);
                }
            }
        }
        // cols 256..259 = router weights (pair with b2 rows of W2'); 260..287 zero
        #pragma unroll
        for (int i = 0; i < 2; ++i) {
            int idx = i * 512 + tid;           // 32 rows x 32 cols
            int row = idx >> 5, c = idx & 31;
            lx[row * HS + 256 + c] = (c < 4) ? f2bf(lw[row * 4 + c]) : (unsigned short)0;
        }
    }
    __syncthreads();

    // ---- phase 3: GEMM2  OUT[32][512] = H[32][288] @ W2'; wave w owns cols [64w,64w+64),
    //      2 N-passes of 32 cols to keep acc at 16 regs ----
    float* ot = out + t0 * 512;
    #pragma unroll
    for (int np = 0; np < 2; ++np) {
        v4f acc2[2][2];
        #pragma unroll
        for (int mt = 0; mt < 2; ++mt)
            #pragma unroll
            for (int nt = 0; nt < 2; ++nt)
                acc2[mt][nt][0] = acc2[mt][nt][1] = acc2[mt][nt][2] = acc2[mt][nt][3] = 0.f;

        for (int kb = 0; kb < 9; ++kb) {
            v8s a[2], b[2];
            #pragma unroll
            for (int mt = 0; mt < 2; ++mt)
                a[mt] = *(const v8s*)(const void*)&lx[(16 * mt + lr) * HS + kb * 32 + lq * 8];
            #pragma unroll
            for (int nt = 0; nt < 2; ++nt)
                b[nt] = *(const v8s*)(const void*)&w2p[(size_t)(kb * 32 + 4 * wv + 2 * np + nt) * 512 + lr * 32 + lq * 8];
            #pragma unroll
            for (int mt = 0; mt < 2; ++mt)
                #pragma unroll
                for (int nt = 0; nt < 2; ++nt)
                    acc2[mt][nt] = __builtin_amdgcn_mfma_f32_16x16x32_bf16(a[mt], b[nt], acc2[mt][nt], 0, 0, 0);
        }

        #pragma unroll
        for (int mt = 0; mt < 2; ++mt)
            #pragma unroll
            for (int nt = 0; nt < 2; ++nt)
                #pragma unroll
                for (int r = 0; r < 4; ++r) {
                    int row = 16 * mt + lq * 4 + r;
                    int col = 64 * wv + 32 * np + 16 * nt + lr;
                    ot[row * 512 + col] = acc2[mt][nt][r];
                }
    }
}

extern "C" void kernel_launch(void* const* d_in, const int* in_sizes, int n_in,
                              void* d_out, int out_size, void* d_ws, size_t ws_size,
                              hipStream_t stream) {
    const float* x  = (const float*)d_in[0];
    const float* rw = (const float*)d_in[1];
    const float* rb = (const float*)d_in[2];
    const float* w1 = (const float*)d_in[3];
    const float* b1 = (const float*)d_in[4];
    const float* w2 = (const float*)d_in[5];
    const float* b2 = (const float*)d_in[6];

    unsigned short* w1p = (unsigned short*)d_ws;      // 131072 elems
    unsigned short* w2p = w1p + 131072;               // 147456 elems
    unsigned short* rp  = w2p + 147456;               // 8192 elems  (total ~573 KB)

    moe_prep<<<1120, 256, 0, stream>>>(w1, w2, b2, rw, w1p, w2p, rp);
    moe_main<<<1024, 512, 0, stream>>>(x, rb, b1, w1p, w2p, rp, (float*)d_out);
}